// Round 5
// baseline (228.693 us; speedup 1.0000x reference)
//
#include <hip/hip_runtime.h>
#include <hip/hip_bf16.h>
#include <math.h>

constexpr int N   = 4096;   // nodes
constexpr int F   = 256;    // IN_FEAT (= NH*HID)
constexpr int NH  = 8;      // heads
constexpr int HID = 32;     // hidden per head
constexpr float SLOPE = 0.2f;

using frag_ab = __attribute__((ext_vector_type(8))) short;  // 8 bf16
using frag_cd = __attribute__((ext_vector_type(4))) float;  // 4 fp32

__device__ inline unsigned short f2bf(float x) {  // RNE fp32->bf16
  unsigned int u = __float_as_uint(x);
  unsigned int r = (u + 0x7fffu + ((u >> 16) & 1u)) >> 16;
  return (unsigned short)r;
}

// ---------------- K0: cast h and W to bf16 ----------------
__global__ __launch_bounds__(256) void k_cast(const float* __restrict__ h,
                                              const float* __restrict__ W,
                                              unsigned short* __restrict__ hb) {
  const int idx8 = (blockIdx.x * 256 + threadIdx.x) * 8;
  const float* src = (idx8 < N * F) ? (h + idx8) : (W + idx8 - N * F);
  const float4 v0 = *(const float4*)src;
  const float4 v1 = *(const float4*)(src + 4);
  unsigned short tmp[8];
  tmp[0] = f2bf(v0.x); tmp[1] = f2bf(v0.y); tmp[2] = f2bf(v0.z); tmp[3] = f2bf(v0.w);
  tmp[4] = f2bf(v1.x); tmp[5] = f2bf(v1.y); tmp[6] = f2bf(v1.z); tmp[7] = f2bf(v1.w);
  *(int4*)(hb + idx8) = *(int4*)tmp;
}

// ---------------- K1: gT = (h @ W^T)^T in bf16, via MFMA ----------------
// one wave per 16x16 tile; C layout (col=n16=feature, row=quad*4+reg=node)
// writes the TRANSPOSE naturally: 4 consecutive j per lane -> 8B store.
__global__ __launch_bounds__(256) void k_mm(const unsigned short* __restrict__ hb,
                                            const unsigned short* __restrict__ Wb,
                                            unsigned short* __restrict__ gT) {
  const int t    = threadIdx.x;
  const int lane = t & 63;
  const int tile = blockIdx.x * 4 + (t >> 6);
  const int mt   = tile >> 4, nt = tile & 15;
  const int m0 = mt * 16, n0 = nt * 16;
  const int n16 = lane & 15, quad = lane >> 4;
  frag_cd acc = {0.f, 0.f, 0.f, 0.f};
  const unsigned short* ap = hb + (size_t)(m0 + n16) * F + quad * 8;
  const unsigned short* bp = Wb + (size_t)(n0 + n16) * F + quad * 8;
#pragma unroll
  for (int ks = 0; ks < F / 32; ++ks) {
    const frag_ab af = *(const frag_ab*)(ap + ks * 32);
    const frag_ab bf = *(const frag_ab*)(bp + ks * 32);
    acc = __builtin_amdgcn_mfma_f32_16x16x32_bf16(af, bf, acc, 0, 0, 0);
  }
  unsigned short tmp[4];
#pragma unroll
  for (int reg = 0; reg < 4; ++reg) tmp[reg] = f2bf(acc[reg]);
  *(int2*)(gT + (size_t)(n0 + n16) * N + m0 + quad * 4) = *(int2*)tmp;
}

// ---------------- K2a: U[c][k] = sum_f W[head*32+f][k] * a[side*32+f] ----------------
// c = side*8 + head; exact reassociation: s = (hW^T)a = h(W^T a).
__global__ __launch_bounds__(256) void k_u(const float* __restrict__ W,
                                           const float* __restrict__ a,
                                           float* __restrict__ U) {
  const int c = blockIdx.x, k = threadIdx.x;
  const int head = c & 7, side = c >> 3;
  float acc = 0.f;
#pragma unroll
  for (int f = 0; f < 32; ++f)
    acc += W[(size_t)(head * 32 + f) * F + k] * a[side * 32 + f];
  U[c * F + k] = acc;
}

// ---------------- K2b: s = h @ U ; fused exp -> RT, BT, DT ----------------
// RT[n][h] = exp(-0.8 s_l)   (the only per-i constant k_agg needs)
// BT[h][n] = exp(s_r), DT[h][n] = exp(0.2 s_r)   (fp32, j-contiguous)
__global__ __launch_bounds__(256) void k_s(const float* __restrict__ h,
                                           const float* __restrict__ U,
                                           float* __restrict__ RT,
                                           float* __restrict__ BT,
                                           float* __restrict__ DT) {
  __shared__ float hs[16][260];
  __shared__ float Us[16][260];
  const int t = threadIdx.x;
  const int i0 = blockIdx.x * 16;
  {
    const int r = t >> 4, s0 = (t & 15) * 16;
    const float4* src = (const float4*)(h + (size_t)(i0 + r) * F + s0);
    const float4* usr = (const float4*)(U + (size_t)r * F + s0);
#pragma unroll
    for (int q = 0; q < 4; ++q) {
      *(float4*)&hs[r][s0 + q * 4] = src[q];
      *(float4*)&Us[r][s0 + q * 4] = usr[q];
    }
  }
  __syncthreads();
  const int r = t >> 4, c = t & 15;
  float acc = 0.f;
#pragma unroll
  for (int k4 = 0; k4 < 64; ++k4) {
    const float4 hv = *(const float4*)&hs[r][k4 * 4];
    const float4 uv = *(const float4*)&Us[c][k4 * 4];
    acc += hv.x * uv.x + hv.y * uv.y + hv.z * uv.z + hv.w * uv.w;
  }
  const int n = i0 + r;
  if (c < 8) {
    RT[(size_t)n * NH + c] = __expf(-0.8f * acc);
  } else {
    const int hd = c - 8;
    BT[(size_t)hd * N + n] = __expf(acc);
    DT[(size_t)hd * N + n] = __expf(SLOPE * acc);
  }
}

// ---------------- K3: adjacency bitmask (pure ballot, HBM-bound) ----------------
__global__ __launch_bounds__(256) void k_bits(const int* __restrict__ adj,
                                              unsigned int* __restrict__ bits) {
  const int t = threadIdx.x, lane = t & 63, wv = t >> 6;
  const int row = blockIdx.x * 4 + wv;
  const int4* arow = (const int4*)(adj + (size_t)row * N);
#pragma unroll
  for (int c = 0; c < 16; ++c) {
    const int4 av = arow[c * 64 + lane];
    unsigned int v = (av.x != 0 ? 1u : 0u) | (av.y != 0 ? 2u : 0u) |
                     (av.z != 0 ? 4u : 0u) | (av.w != 0 ? 8u : 0u);
    v <<= ((lane & 7) * 4);
    v |= __shfl_xor(v, 1);
    v |= __shfl_xor(v, 2);
    v |= __shfl_xor(v, 4);
    if ((lane & 7) == 0) bits[(size_t)row * (N / 32) + c * 8 + (lane >> 3)] = v;
  }
}

// ---------------- K4: barrier-free streaming MFMA aggregation ----------------
// w'_ij = adj * max(B_j, Ri*D_j)  (per-row exp(si) factor cancels in softmax).
// No LDS, no __syncthreads: gT/B/D/bits all stream through L1/L2.
constexpr int TI = 32;
constexpr int NSPLIT = 4;

__global__ __launch_bounds__(256, 4) void k_agg(
    const unsigned short* __restrict__ gT,
    const float* __restrict__ RT,
    const float* __restrict__ BT, const float* __restrict__ DT,
    const unsigned int* __restrict__ bits,
    float* __restrict__ outp, float* __restrict__ lbuf) {
  const int t    = threadIdx.x;
  const int lane = t & 63;
  const int wv   = t >> 6;
  const int isub = wv & 1;
  const int hh   = wv >> 1;
  const int b    = blockIdx.x;
  const int hp   = b & 3;
  const int js   = (b >> 2) & (NSPLIT - 1);
  const int i0   = (b >> 4) * TI;
  const int head = hp * 2 + hh;

  const int n16  = lane & 15;
  const int quad = lane >> 4;

  const int myi  = i0 + isub * 16 + n16;
  const float Ri = RT[(size_t)myi * NH + head];

  const float* Bp = BT + (size_t)head * N + js * 1024;
  const float* Dp = DT + (size_t)head * N + js * 1024;
  const unsigned short* g0 = gT + (size_t)(head * 32 + n16) * N + js * 1024;
  const unsigned short* g1 = g0 + (size_t)16 * N;
  const uint4* bp4 = (const uint4*)(bits + (size_t)myi * (N / 32) + js * 32);

  frag_cd acc0 = {0.f, 0.f, 0.f, 0.f};
  frag_cd acc1 = {0.f, 0.f, 0.f, 0.f};
  frag_cd accl = {0.f, 0.f, 0.f, 0.f};
  frag_ab fone;
#pragma unroll
  for (int u = 0; u < 8; ++u) fone[u] = (short)0x3F80;  // bf16 1.0

  for (int c8 = 0; c8 < 8; ++c8) {
    const uint4 bw = bp4[c8];
#pragma unroll
    for (int ks = 0; ks < 4; ++ks) {
      const int off = c8 * 128 + ks * 32 + quad * 8;
      const float4 B0 = *(const float4*)(Bp + off);
      const float4 B1 = *(const float4*)(Bp + off + 4);
      const float4 D0 = *(const float4*)(Dp + off);
      const float4 D1 = *(const float4*)(Dp + off + 4);
      const frag_ab b0 = *(const frag_ab*)(g0 + off);
      const frag_ab b1 = *(const frag_ab*)(g1 + off);
      const unsigned int word = ks == 0 ? bw.x : ks == 1 ? bw.y : ks == 2 ? bw.z : bw.w;
      const unsigned int mb = (word >> (quad * 8)) & 0xffu;

      const float Bu[8] = {B0.x, B0.y, B0.z, B0.w, B1.x, B1.y, B1.z, B1.w};
      const float Du[8] = {D0.x, D0.y, D0.z, D0.w, D1.x, D1.y, D1.z, D1.w};
      int packed[4];
#pragma unroll
      for (int p = 0; p < 4; ++p) {
        const float w0 = fmaxf(Bu[2 * p], Ri * Du[2 * p]);
        const float w1 = fmaxf(Bu[2 * p + 1], Ri * Du[2 * p + 1]);
        const __hip_bfloat162 bp2 = __float22bfloat162_rn(make_float2(w0, w1));
        unsigned int pk;
        __builtin_memcpy(&pk, &bp2, 4);
        const unsigned int d  = (mb >> (2 * p)) & 3u;
        const unsigned int sp = (d | (d << 15)) & 0x10001u;
        pk &= sp * 0xFFFFu;  // {0|0xFFFF} per 16-bit half: adjacency mask
        packed[p] = (int)pk;
      }
      frag_ab af;
      __builtin_memcpy(&af, packed, 16);
      acc0 = __builtin_amdgcn_mfma_f32_16x16x32_bf16(af, b0, acc0, 0, 0, 0);
      acc1 = __builtin_amdgcn_mfma_f32_16x16x32_bf16(af, b1, acc1, 0, 0, 0);
      accl = __builtin_amdgcn_mfma_f32_16x16x32_bf16(af, fone, accl, 0, 0, 0);
    }
  }
#pragma unroll
  for (int reg = 0; reg < 4; ++reg) {
    const int row = quad * 4 + reg;
    const int gi = i0 + isub * 16 + row;
    atomicAdd(&outp[(size_t)gi * F + head * HID + n16], acc0[reg]);
    atomicAdd(&outp[(size_t)gi * F + head * HID + 16 + n16], acc1[reg]);
    if (n16 == 0) atomicAdd(&lbuf[(size_t)gi * NH + head], accl[reg]);
  }
}

// ---------------- K5: normalize ----------------
__global__ __launch_bounds__(256) void k_norm(float* __restrict__ outp,
                                              const float* __restrict__ lbuf) {
  const int idx = blockIdx.x * 256 + threadIdx.x;  // float4 index
  const int i = idx >> 6, fq = idx & 63;
  const int hh = fq >> 3;
  const float inv = 1.f / lbuf[(size_t)i * NH + hh];
  float4 v = *(float4*)(outp + (size_t)idx * 4);
  v.x *= inv; v.y *= inv; v.z *= inv; v.w *= inv;
  *(float4*)(outp + (size_t)idx * 4) = v;
}

extern "C" void kernel_launch(void* const* d_in, const int* in_sizes, int n_in,
                              void* d_out, int out_size, void* d_ws, size_t ws_size,
                              hipStream_t stream) {
  const float* h   = (const float*)d_in[0];
  const float* W   = (const float*)d_in[1];
  const float* a   = (const float*)d_in[2];
  const int*   adj = (const int*)d_in[3];
  float* out = (float*)d_out;

  // workspace (~4.7 MB)
  char* ws = (char*)d_ws;
  unsigned short* hb = (unsigned short*)ws;  ws += (size_t)(N * F + F * F) * 2;
  unsigned short* Wb = hb + (size_t)N * F;
  unsigned short* gT = (unsigned short*)ws;  ws += (size_t)N * F * 2;
  unsigned int* bits = (unsigned int*)ws;    ws += (size_t)N * (N / 32) * 4;
  float* U    = (float*)ws;                  ws += 16 * F * 4;
  float* RT   = (float*)ws;                  ws += (size_t)N * NH * 4;
  float* BT   = (float*)ws;                  ws += (size_t)N * NH * 4;
  float* DT   = (float*)ws;                  ws += (size_t)N * NH * 4;
  float* lbuf = (float*)ws;                  ws += (size_t)N * NH * 4;

  hipMemsetAsync(out, 0, (size_t)N * F * 4, stream);
  hipMemsetAsync(lbuf, 0, (size_t)N * NH * 4, stream);

  k_cast<<<dim3((N * F + F * F) / (256 * 8)), dim3(256), 0, stream>>>(h, W, hb);
  k_u<<<dim3(16), dim3(256), 0, stream>>>(W, a, U);
  k_s<<<dim3(N / 16), dim3(256), 0, stream>>>(h, U, RT, BT, DT);
  k_mm<<<dim3((N / 16) * (F / 16) / 4), dim3(256), 0, stream>>>(hb, Wb, gT);
  k_bits<<<dim3(N / 4), dim3(256), 0, stream>>>(adj, bits);
  k_agg<<<dim3((N / TI) * 4 * NSPLIT), dim3(256), 0, stream>>>(
      gT, RT, BT, DT, bits, out, lbuf);
  k_norm<<<dim3(N * F / 4 / 256), dim3(256), 0, stream>>>(out, lbuf);
}

// Round 6
// 184.816 us; speedup vs baseline: 1.2374x; 1.2374x over previous
//
#include <hip/hip_runtime.h>
#include <hip/hip_bf16.h>
#include <math.h>

constexpr int N   = 4096;   // nodes
constexpr int F   = 256;    // IN_FEAT (= NH*HID)
constexpr int NH  = 8;      // heads
constexpr int HID = 32;     // hidden per head
constexpr float SLOPE = 0.2f;

using frag_ab = __attribute__((ext_vector_type(8))) short;  // 8 bf16
using frag_cd = __attribute__((ext_vector_type(4))) float;  // 4 fp32

__device__ inline unsigned short f2bf(float x) {  // RNE fp32->bf16
  unsigned int u = __float_as_uint(x);
  unsigned int r = (u + 0x7fffu + ((u >> 16) & 1u)) >> 16;
  return (unsigned short)r;
}

// ================= K_PRE: fused input-layer =================
// blocks [0,544): cast h,W -> bf16
// blocks [544,560): U = W^T a  (16 cols x 256 rows)
// blocks [560,1584): adjacency bitmask (4 rows/block)
// blocks [1584,2608): zero out
// blocks [2608,2640): zero lbuf
__global__ __launch_bounds__(256) void k_pre(const float* __restrict__ h,
                                             const float* __restrict__ W,
                                             const float* __restrict__ a,
                                             const int* __restrict__ adj,
                                             unsigned short* __restrict__ hb,
                                             float* __restrict__ U,
                                             unsigned int* __restrict__ bits,
                                             float* __restrict__ outp,
                                             float* __restrict__ lbuf) {
  const int b = blockIdx.x, t = threadIdx.x;
  if (b < 544) {
    const int idx8 = (b * 256 + t) * 8;
    const float* src = (idx8 < N * F) ? (h + idx8) : (W + idx8 - N * F);
    const float4 v0 = *(const float4*)src;
    const float4 v1 = *(const float4*)(src + 4);
    unsigned short tmp[8];
    tmp[0] = f2bf(v0.x); tmp[1] = f2bf(v0.y); tmp[2] = f2bf(v0.z); tmp[3] = f2bf(v0.w);
    tmp[4] = f2bf(v1.x); tmp[5] = f2bf(v1.y); tmp[6] = f2bf(v1.z); tmp[7] = f2bf(v1.w);
    *(int4*)(hb + idx8) = *(int4*)tmp;
  } else if (b < 560) {
    const int c = b - 544, k = t;
    const int head = c & 7, side = c >> 3;
    float acc = 0.f;
#pragma unroll
    for (int f = 0; f < 32; ++f)
      acc += W[(size_t)(head * 32 + f) * F + k] * a[side * 32 + f];
    U[c * F + k] = acc;
  } else if (b < 1584) {
    const int lane = t & 63, wv = t >> 6;
    const int row = (b - 560) * 4 + wv;
    const int4* arow = (const int4*)(adj + (size_t)row * N);
#pragma unroll
    for (int c = 0; c < 16; ++c) {
      const int4 av = arow[c * 64 + lane];
      unsigned int v = (av.x != 0 ? 1u : 0u) | (av.y != 0 ? 2u : 0u) |
                       (av.z != 0 ? 4u : 0u) | (av.w != 0 ? 8u : 0u);
      v <<= ((lane & 7) * 4);
      v |= __shfl_xor(v, 1);
      v |= __shfl_xor(v, 2);
      v |= __shfl_xor(v, 4);
      if ((lane & 7) == 0) bits[(size_t)row * (N / 32) + c * 8 + (lane >> 3)] = v;
    }
  } else if (b < 2608) {
    *(float4*)(outp + ((size_t)(b - 1584) * 256 + t) * 4) =
        make_float4(0.f, 0.f, 0.f, 0.f);
  } else {
    *(float4*)(lbuf + ((size_t)(b - 2608) * 256 + t) * 4) =
        make_float4(0.f, 0.f, 0.f, 0.f);
  }
}

// ================= K_MID: fused second layer =================
// blocks [0,256): s = h @ U -> RT = exp(-0.8 s_l); BT = exp(s_r), DT = exp(0.2 s_r)
// blocks [256,1280): gT = (hb @ Wb^T)^T bf16 via MFMA (1 wave / 16x16 tile)
__global__ __launch_bounds__(256) void k_mid(const float* __restrict__ h,
                                             const float* __restrict__ U,
                                             const unsigned short* __restrict__ hb,
                                             const unsigned short* __restrict__ Wb,
                                             float* __restrict__ RT,
                                             float* __restrict__ BT,
                                             float* __restrict__ DT,
                                             unsigned short* __restrict__ gT) {
  __shared__ float hs[16][260];
  __shared__ float Us[16][260];
  const int b = blockIdx.x, t = threadIdx.x;
  if (b < 256) {
    const int i0 = b * 16;
    {
      const int r = t >> 4, s0 = (t & 15) * 16;
      const float4* src = (const float4*)(h + (size_t)(i0 + r) * F + s0);
      const float4* usr = (const float4*)(U + (size_t)r * F + s0);
#pragma unroll
      for (int q = 0; q < 4; ++q) {
        *(float4*)&hs[r][s0 + q * 4] = src[q];
        *(float4*)&Us[r][s0 + q * 4] = usr[q];
      }
    }
    __syncthreads();
    const int r = t >> 4, c = t & 15;
    float acc = 0.f;
#pragma unroll
    for (int k4 = 0; k4 < 64; ++k4) {
      const float4 hv = *(const float4*)&hs[r][k4 * 4];
      const float4 uv = *(const float4*)&Us[c][k4 * 4];
      acc += hv.x * uv.x + hv.y * uv.y + hv.z * uv.z + hv.w * uv.w;
    }
    const int n = i0 + r;
    if (c < 8) {
      RT[(size_t)n * NH + c] = __expf(-0.8f * acc);
    } else {
      const int hd = c - 8;
      BT[(size_t)hd * N + n] = __expf(acc);
      DT[(size_t)hd * N + n] = __expf(SLOPE * acc);
    }
  } else {
    const int lane = t & 63;
    const int tile = (b - 256) * 4 + (t >> 6);
    const int mt = tile >> 4, nt = tile & 15;
    const int m0 = mt * 16, n0 = nt * 16;
    const int n16 = lane & 15, quad = lane >> 4;
    frag_cd acc = {0.f, 0.f, 0.f, 0.f};
    const unsigned short* ap = hb + (size_t)(m0 + n16) * F + quad * 8;
    const unsigned short* bp = Wb + (size_t)(n0 + n16) * F + quad * 8;
#pragma unroll
    for (int ks = 0; ks < F / 32; ++ks) {
      const frag_ab af = *(const frag_ab*)(ap + ks * 32);
      const frag_ab bf = *(const frag_ab*)(bp + ks * 32);
      acc = __builtin_amdgcn_mfma_f32_16x16x32_bf16(af, bf, acc, 0, 0, 0);
    }
    unsigned short tmp[4];
#pragma unroll
    for (int reg = 0; reg < 4; ++reg) tmp[reg] = f2bf(acc[reg]);
    *(int2*)(gT + (size_t)(n0 + n16) * N + m0 + quad * 4) = *(int2*)tmp;
  }
}

// ================= K_AGG: LDS-staged MFMA flash aggregation =================
// w'_ij = adj * max(B_j, Ri*D_j); gT chunk in LDS (stride 140 -> conflict-free),
// fp32 B/D quad-broadcast from global, bits one uint4 per 128-j chunk.
constexpr int TI = 32;
constexpr int NSPLIT = 4;

__global__ __launch_bounds__(256, 6) void k_agg(
    const unsigned short* __restrict__ gT,
    const float* __restrict__ RT,
    const float* __restrict__ BT, const float* __restrict__ DT,
    const unsigned int* __restrict__ bits,
    float* __restrict__ outp, float* __restrict__ lbuf) {
  __shared__ __align__(16) unsigned short sB[64][140];  // 140 = 70 words: 16 rows -> 16 banks

  const int t    = threadIdx.x;
  const int lane = t & 63;
  const int wv   = t >> 6;
  const int isub = wv & 1;
  const int hh   = wv >> 1;
  const int b    = blockIdx.x;
  const int hp   = b & 3;
  const int js   = (b >> 2) & (NSPLIT - 1);
  const int i0   = (b >> 4) * TI;
  const int head = hp * 2 + hh;

  const int n16  = lane & 15;
  const int quad = lane >> 4;

  const int myi  = i0 + isub * 16 + n16;
  const float Ri = RT[(size_t)myi * NH + head];

  const float* Bp = BT + (size_t)head * N + js * 1024;
  const float* Dp = DT + (size_t)head * N + js * 1024;
  const uint4* bp4 = (const uint4*)(bits + (size_t)myi * (N / 32) + js * 32);

  frag_cd acc0 = {0.f, 0.f, 0.f, 0.f};
  frag_cd acc1 = {0.f, 0.f, 0.f, 0.f};
  frag_cd accl = {0.f, 0.f, 0.f, 0.f};
  frag_ab fone;
#pragma unroll
  for (int u = 0; u < 8; ++u) fone[u] = (short)0x3F80;  // bf16 1.0

  const int sr = t >> 2, ss0 = t & 3;  // gT staging persona

  for (int c8 = 0; c8 < 8; ++c8) {
    const int j0 = c8 * 128;
    __syncthreads();
    {  // stage gT rows (64 feats x 128 j, bf16)
      const unsigned short* src = gT + (size_t)(hp * 64 + sr) * N + js * 1024 + j0;
#pragma unroll
      for (int s = 0; s < 4; ++s) {
        const int seg = ss0 + s * 4;
        *(int4*)&sB[sr][seg * 8] = *(const int4*)(src + seg * 8);
      }
    }
    const uint4 bw = bp4[c8];
    __syncthreads();
#pragma unroll
    for (int ks = 0; ks < 4; ++ks) {
      const int lo  = ks * 32 + quad * 8;   // offset within chunk
      const int off = j0 + lo;              // offset within 1024-j slice
      const float4 B0 = *(const float4*)(Bp + off);
      const float4 B1 = *(const float4*)(Bp + off + 4);
      const float4 D0 = *(const float4*)(Dp + off);
      const float4 D1 = *(const float4*)(Dp + off + 4);
      const frag_ab b0 = *(const frag_ab*)&sB[hh * 32 + n16][lo];
      const frag_ab b1 = *(const frag_ab*)&sB[hh * 32 + 16 + n16][lo];
      const unsigned int word = ks == 0 ? bw.x : ks == 1 ? bw.y : ks == 2 ? bw.z : bw.w;
      const unsigned int mb = (word >> (quad * 8)) & 0xffu;

      const float Bu[8] = {B0.x, B0.y, B0.z, B0.w, B1.x, B1.y, B1.z, B1.w};
      const float Du[8] = {D0.x, D0.y, D0.z, D0.w, D1.x, D1.y, D1.z, D1.w};
      int packed[4];
#pragma unroll
      for (int p = 0; p < 4; ++p) {
        float w0 = fmaxf(Bu[2 * p],     Ri * Du[2 * p]);
        float w1 = fmaxf(Bu[2 * p + 1], Ri * Du[2 * p + 1]);
        w0 = (mb & (1u << (2 * p)))     ? w0 : 0.f;
        w1 = (mb & (1u << (2 * p + 1))) ? w1 : 0.f;
        const __hip_bfloat162 bp2 = __float22bfloat162_rn(make_float2(w0, w1));
        __builtin_memcpy(&packed[p], &bp2, 4);
      }
      frag_ab af;
      __builtin_memcpy(&af, packed, 16);
      acc0 = __builtin_amdgcn_mfma_f32_16x16x32_bf16(af, b0, acc0, 0, 0, 0);
      acc1 = __builtin_amdgcn_mfma_f32_16x16x32_bf16(af, b1, acc1, 0, 0, 0);
      accl = __builtin_amdgcn_mfma_f32_16x16x32_bf16(af, fone, accl, 0, 0, 0);
    }
  }
#pragma unroll
  for (int reg = 0; reg < 4; ++reg) {
    const int row = quad * 4 + reg;
    const int gi = i0 + isub * 16 + row;
    atomicAdd(&outp[(size_t)gi * F + head * HID + n16], acc0[reg]);
    atomicAdd(&outp[(size_t)gi * F + head * HID + 16 + n16], acc1[reg]);
    if (n16 == 0) atomicAdd(&lbuf[(size_t)gi * NH + head], accl[reg]);
  }
}

// ================= K_NORM =================
__global__ __launch_bounds__(256) void k_norm(float* __restrict__ outp,
                                              const float* __restrict__ lbuf) {
  const int idx = blockIdx.x * 256 + threadIdx.x;  // float4 index
  const int i = idx >> 6, fq = idx & 63;
  const int hh = fq >> 3;
  const float inv = 1.f / lbuf[(size_t)i * NH + hh];
  float4 v = *(float4*)(outp + (size_t)idx * 4);
  v.x *= inv; v.y *= inv; v.z *= inv; v.w *= inv;
  *(float4*)(outp + (size_t)idx * 4) = v;
}

extern "C" void kernel_launch(void* const* d_in, const int* in_sizes, int n_in,
                              void* d_out, int out_size, void* d_ws, size_t ws_size,
                              hipStream_t stream) {
  const float* h   = (const float*)d_in[0];
  const float* W   = (const float*)d_in[1];
  const float* a   = (const float*)d_in[2];
  const int*   adj = (const int*)d_in[3];
  float* out = (float*)d_out;

  // workspace (~6.8 MB)
  char* ws = (char*)d_ws;
  unsigned short* hb = (unsigned short*)ws;  ws += (size_t)(N * F + F * F) * 2;
  unsigned short* Wb = hb + (size_t)N * F;
  unsigned short* gT = (unsigned short*)ws;  ws += (size_t)N * F * 2;
  unsigned int* bits = (unsigned int*)ws;    ws += (size_t)N * (N / 32) * 4;
  float* U    = (float*)ws;                  ws += 16 * F * 4;
  float* RT   = (float*)ws;                  ws += (size_t)N * NH * 4;
  float* BT   = (float*)ws;                  ws += (size_t)N * NH * 4;
  float* DT   = (float*)ws;                  ws += (size_t)N * NH * 4;
  float* lbuf = (float*)ws;                  ws += (size_t)N * NH * 4;

  k_pre<<<dim3(2640), dim3(256), 0, stream>>>(h, W, a, adj, hb, U, bits, out, lbuf);
  k_mid<<<dim3(1280), dim3(256), 0, stream>>>(h, U, hb, Wb, RT, BT, DT, gT);
  k_agg<<<dim3((N / TI) * 4 * NSPLIT), dim3(256), 0, stream>>>(
      gT, RT, BT, DT, bits, out, lbuf);
  k_norm<<<dim3(N * F / 4 / 256), dim3(256), 0, stream>>>(out, lbuf);
}

// Round 8
// 163.950 us; speedup vs baseline: 1.3949x; 1.1273x over previous
//
#include <hip/hip_runtime.h>
#include <hip/hip_bf16.h>
#include <math.h>

constexpr int N   = 4096;   // nodes
constexpr int F   = 256;    // IN_FEAT (= NH*HID)
constexpr int NH  = 8;      // heads
constexpr int HID = 32;     // hidden per head
constexpr float SLOPE = 0.2f;

using frag_ab  = __attribute__((ext_vector_type(8))) short;   // 8 bf16
using frag_cd  = __attribute__((ext_vector_type(4))) float;   // 4 fp32
using frag_c16 = __attribute__((ext_vector_type(16))) float;  // 16 fp32

__device__ inline unsigned short f2bf(float x) {  // RNE fp32->bf16
  unsigned int u = __float_as_uint(x);
  unsigned int r = (u + 0x7fffu + ((u >> 16) & 1u)) >> 16;
  return (unsigned short)r;
}

// ================= K_PRE: fused input-layer =================
// [0,544): cast h,W -> bf16 | [544,560): U = W^T a | [560,2608): adj bitmask
// [2608,2864): zero out (4 float4/thread) | [2864,2896): zero lbuf
__global__ __launch_bounds__(256) void k_pre(const float* __restrict__ h,
                                             const float* __restrict__ W,
                                             const float* __restrict__ a,
                                             const int* __restrict__ adj,
                                             unsigned short* __restrict__ hb,
                                             float* __restrict__ U,
                                             unsigned int* __restrict__ bits,
                                             float* __restrict__ outp,
                                             float* __restrict__ lbuf) {
  const int b = blockIdx.x, t = threadIdx.x;
  if (b < 544) {
    const int idx8 = (b * 256 + t) * 8;
    const float* src = (idx8 < N * F) ? (h + idx8) : (W + idx8 - N * F);
    const float4 v0 = *(const float4*)src;
    const float4 v1 = *(const float4*)(src + 4);
    unsigned short tmp[8];
    tmp[0] = f2bf(v0.x); tmp[1] = f2bf(v0.y); tmp[2] = f2bf(v0.z); tmp[3] = f2bf(v0.w);
    tmp[4] = f2bf(v1.x); tmp[5] = f2bf(v1.y); tmp[6] = f2bf(v1.z); tmp[7] = f2bf(v1.w);
    *(int4*)(hb + idx8) = *(int4*)tmp;
  } else if (b < 560) {
    const int c = b - 544, k = t;
    const int head = c & 7, side = c >> 3;
    float acc = 0.f;
#pragma unroll
    for (int f = 0; f < 32; ++f)
      acc += W[(size_t)(head * 32 + f) * F + k] * a[side * 32 + f];
    U[c * F + k] = acc;
  } else if (b < 2608) {
    const int lane = t & 63, w = t >> 6;
    const int row  = (b - 560) * 2 + (w >> 1);
    const int half = w & 1;
    const int4* arow = (const int4*)(adj + (size_t)row * N) + half * 512;
    unsigned int* brow = bits + (size_t)row * (N / 32) + half * 64;
#pragma unroll
    for (int c = 0; c < 8; ++c) {
      const int4 av = arow[c * 64 + lane];
      unsigned int v = (av.x != 0 ? 1u : 0u) | (av.y != 0 ? 2u : 0u) |
                       (av.z != 0 ? 4u : 0u) | (av.w != 0 ? 8u : 0u);
      v <<= ((lane & 7) * 4);
      v |= __shfl_xor(v, 1);
      v |= __shfl_xor(v, 2);
      v |= __shfl_xor(v, 4);
      if ((lane & 7) == 0) brow[c * 8 + (lane >> 3)] = v;
    }
  } else if (b < 2864) {
    const int base = (b - 2608) * 256 + t;  // 65536 bases
#pragma unroll
    for (int q = 0; q < 4; ++q)
      *(float4*)(outp + ((size_t)q * 65536 + base) * 4) =
          make_float4(0.f, 0.f, 0.f, 0.f);
  } else {
    *(float4*)(lbuf + ((size_t)(b - 2864) * 256 + t) * 4) =
        make_float4(0.f, 0.f, 0.f, 0.f);
  }
}

// ================= K_MID: fused second layer =================
// [0,256): s = h @ U -> RT = exp(-0.8 s_l); BDT = pack(bf16 exp(s_r), bf16 exp(0.2 s_r))
// [256,1280): gT = (hb @ Wb^T)^T bf16 via MFMA
__global__ __launch_bounds__(256) void k_mid(const float* __restrict__ h,
                                             const float* __restrict__ U,
                                             const unsigned short* __restrict__ hb,
                                             const unsigned short* __restrict__ Wb,
                                             float* __restrict__ RT,
                                             unsigned int* __restrict__ BDT,
                                             unsigned short* __restrict__ gT) {
  __shared__ float hs[16][260];
  __shared__ float Us[16][260];
  const int b = blockIdx.x, t = threadIdx.x;
  if (b < 256) {
    const int i0 = b * 16;
    {
      const int r = t >> 4, s0 = (t & 15) * 16;
      const float4* src = (const float4*)(h + (size_t)(i0 + r) * F + s0);
      const float4* usr = (const float4*)(U + (size_t)r * F + s0);
#pragma unroll
      for (int q = 0; q < 4; ++q) {
        *(float4*)&hs[r][s0 + q * 4] = src[q];
        *(float4*)&Us[r][s0 + q * 4] = usr[q];
      }
    }
    __syncthreads();
    const int r = t >> 4, c = t & 15;
    float acc = 0.f;
#pragma unroll
    for (int k4 = 0; k4 < 64; ++k4) {
      const float4 hv = *(const float4*)&hs[r][k4 * 4];
      const float4 uv = *(const float4*)&Us[c][k4 * 4];
      acc += hv.x * uv.x + hv.y * uv.y + hv.z * uv.z + hv.w * uv.w;
    }
    const int n = i0 + r;
    if (c < 8) {
      RT[(size_t)n * NH + c] = __expf(-0.8f * acc);
    } else {
      const int hd = c - 8;
      const unsigned int bw = f2bf(__expf(acc));
      const unsigned int dw = f2bf(__expf(SLOPE * acc));
      BDT[(size_t)hd * N + n] = (bw << 16) | dw;
    }
  } else {
    const int lane = t & 63;
    const int tile = (b - 256) * 4 + (t >> 6);
    const int mt = tile >> 4, nt = tile & 15;
    const int m0 = mt * 16, n0 = nt * 16;
    const int n16 = lane & 15, quad = lane >> 4;
    frag_cd acc = {0.f, 0.f, 0.f, 0.f};
    const unsigned short* ap = hb + (size_t)(m0 + n16) * F + quad * 8;
    const unsigned short* bp = Wb + (size_t)(n0 + n16) * F + quad * 8;
#pragma unroll
    for (int ks = 0; ks < F / 32; ++ks) {
      const frag_ab af = *(const frag_ab*)(ap + ks * 32);
      const frag_ab bf = *(const frag_ab*)(bp + ks * 32);
      acc = __builtin_amdgcn_mfma_f32_16x16x32_bf16(af, bf, acc, 0, 0, 0);
    }
    unsigned short tmp[4];
#pragma unroll
    for (int reg = 0; reg < 4; ++reg) tmp[reg] = f2bf(acc[reg]);
    *(int2*)(gT + (size_t)(n0 + n16) * N + m0 + quad * 4) = *(int2*)tmp;
  }
}

// ================= K_AGG: 32x32 MFMA flash aggregation =================
// block = 32 i x head-pair x 1/4 j; waves: (hd = wv>>1, jh = wv&1).
// Per 16-j step: 1 gT frag (LDS) + 8 BD words (LDS broadcast) + 1 MFMA 32x32x16.
// w'_ij = adj * max(B_j, Ri*D_j); l by VALU; wave-pair merged in LDS, then atomics.
constexpr int TI = 32;
constexpr int NSPLIT = 4;

__global__ __launch_bounds__(256, 6) void k_agg(
    const unsigned short* __restrict__ gT,
    const float* __restrict__ RT,
    const unsigned int* __restrict__ BDT,
    const unsigned int* __restrict__ bits,
    float* __restrict__ outp, float* __restrict__ lbuf) {
  __shared__ __align__(16) unsigned short sB[64][140];  // gT chunk, row=f, col=j
  __shared__ __align__(16) unsigned int sBD[2][128];    // packed B|D per head

  const int t    = threadIdx.x;
  const int lane = t & 63;
  const int wv   = t >> 6;
  const int hd   = wv >> 1;   // head within pair
  const int jh   = wv & 1;    // j-interleave
  const int b    = blockIdx.x;
  const int hp   = b & 3;
  const int js   = (b >> 2) & (NSPLIT - 1);
  const int i0   = (b >> 4) * TI;
  const int head = hp * 2 + hd;

  const int n32 = lane & 31;
  const int kh  = lane >> 5;

  const int myi  = i0 + n32;
  const float Ri = RT[(size_t)myi * NH + head];
  const uint4* bp4 = (const uint4*)(bits + (size_t)myi * (N / 32) + js * 32);

  frag_c16 acc = {0.f, 0.f, 0.f, 0.f, 0.f, 0.f, 0.f, 0.f,
                  0.f, 0.f, 0.f, 0.f, 0.f, 0.f, 0.f, 0.f};
  float lpart = 0.f;

  const int sr = t >> 2, ss0 = t & 3;  // gT staging persona
  const unsigned short* gsrc = gT + (size_t)(hp * 64 + sr) * N + js * 1024;
  const unsigned int*  bdsrc = BDT + (size_t)(hp * 2 + (t >> 7)) * N + js * 1024 + (t & 127);

  for (int c8 = 0; c8 < 8; ++c8) {
    __syncthreads();
    {  // stage gT 64 x 128 bf16 (rows 8B-aligned at stride 280B)
#pragma unroll
      for (int s = 0; s < 4; ++s) {
        const int seg = ss0 + s * 4;
        const int4 v = *(const int4*)(gsrc + c8 * 128 + seg * 8);
        *(int2*)&sB[sr][seg * 8]     = make_int2(v.x, v.y);
        *(int2*)&sB[sr][seg * 8 + 4] = make_int2(v.z, v.w);
      }
    }
    sBD[t >> 7][t & 127] = bdsrc[c8 * 128];
    const uint4 bw = bp4[c8];
    __syncthreads();
#pragma unroll
    for (int sh = 0; sh < 4; ++sh) {
      const int ss = sh * 2 + jh;        // my 16-j step within chunk
      const int jb = ss * 16 + kh * 8;   // my j offset (8 elems)
      const uint4 bdl = *(const uint4*)&sBD[hd][jb];
      const uint4 bdh = *(const uint4*)&sBD[hd][jb + 4];
      const unsigned int w32 =
          (ss >> 1) == 0 ? bw.x : (ss >> 1) == 1 ? bw.y : (ss >> 1) == 2 ? bw.z : bw.w;
      const unsigned int mb = (w32 >> (((ss & 1) << 4) + (kh << 3))) & 0xFFu;

      const unsigned int bdw[8] = {bdl.x, bdl.y, bdl.z, bdl.w,
                                   bdh.x, bdh.y, bdh.z, bdh.w};
      int packed[4];
#pragma unroll
      for (int p = 0; p < 4; ++p) {
        const unsigned int u0 = bdw[2 * p], u1 = bdw[2 * p + 1];
        const float B0 = __uint_as_float(u0 & 0xFFFF0000u);
        const float D0 = __uint_as_float(u0 << 16);
        const float B1 = __uint_as_float(u1 & 0xFFFF0000u);
        const float D1 = __uint_as_float(u1 << 16);
        float w0 = fmaxf(B0, Ri * D0);
        float w1 = fmaxf(B1, Ri * D1);
        w0 = (mb & (1u << (2 * p)))     ? w0 : 0.f;
        w1 = (mb & (1u << (2 * p + 1))) ? w1 : 0.f;
        lpart += w0 + w1;
        const __hip_bfloat162 bp2 = __float22bfloat162_rn(make_float2(w0, w1));
        __builtin_memcpy(&packed[p], &bp2, 4);
      }
      frag_ab af;
      __builtin_memcpy(&af, packed, 16);

      const int frow = hd * 32 + n32;
      const int2 blo = *(const int2*)&sB[frow][jb];
      const int2 bhi = *(const int2*)&sB[frow][jb + 4];
      const int bt[4] = {blo.x, blo.y, bhi.x, bhi.y};
      frag_ab bf;
      __builtin_memcpy(&bf, bt, 16);

      acc = __builtin_amdgcn_mfma_f32_32x32x16_bf16(af, bf, acc, 0, 0, 0);
    }
  }

  // ---- merge wave pairs (jh=1 -> LDS, jh=0 adds), then atomics ----
  float* mrg  = (float*)&sB[0][0];   // [2][32][32] fp32 = 8 KB (aliases sB)
  float* mrgl = (float*)&sBD[0][0];  // [2][32]
  const float lp2 = lpart + __shfl_xor(lpart, 32);  // sum kh halves (per i=n32)
  __syncthreads();
  if (jh == 1) {
#pragma unroll
    for (int reg = 0; reg < 16; ++reg) {
      const int row = (reg & 3) + 8 * (reg >> 2) + 4 * kh;
      mrg[(size_t)(hd * 32 + row) * 32 + n32] = acc[reg];
    }
    if (kh == 0) mrgl[hd * 32 + n32] = lp2;
  }
  __syncthreads();
  if (jh == 0) {
    const float lt = lp2 + mrgl[hd * 32 + n32];
    if (kh == 0) atomicAdd(&lbuf[(size_t)(i0 + n32) * NH + head], lt);
#pragma unroll
    for (int reg = 0; reg < 16; ++reg) {
      const int row = (reg & 3) + 8 * (reg >> 2) + 4 * kh;
      const float v = acc[reg] + mrg[(size_t)(hd * 32 + row) * 32 + n32];
      atomicAdd(&outp[(size_t)(i0 + row) * F + head * HID + n32], v);
    }
  }
}

// ================= K_NORM =================
__global__ __launch_bounds__(256) void k_norm(float* __restrict__ outp,
                                              const float* __restrict__ lbuf) {
  const int idx = blockIdx.x * 256 + threadIdx.x;  // float4 index
  const int i = idx >> 6, fq = idx & 63;
  const int hh = fq >> 3;
  const float inv = 1.f / lbuf[(size_t)i * NH + hh];
  float4 v = *(float4*)(outp + (size_t)idx * 4);
  v.x *= inv; v.y *= inv; v.z *= inv; v.w *= inv;
  *(float4*)(outp + (size_t)idx * 4) = v;
}

extern "C" void kernel_launch(void* const* d_in, const int* in_sizes, int n_in,
                              void* d_out, int out_size, void* d_ws, size_t ws_size,
                              hipStream_t stream) {
  const float* h   = (const float*)d_in[0];
  const float* W   = (const float*)d_in[1];
  const float* a   = (const float*)d_in[2];
  const int*   adj = (const int*)d_in[3];
  float* out = (float*)d_out;

  // workspace (~6.6 MB)
  char* ws = (char*)d_ws;
  unsigned short* hb = (unsigned short*)ws;  ws += (size_t)(N * F + F * F) * 2;
  unsigned short* Wb = hb + (size_t)N * F;
  unsigned short* gT = (unsigned short*)ws;  ws += (size_t)N * F * 2;
  unsigned int* bits = (unsigned int*)ws;    ws += (size_t)N * (N / 32) * 4;
  float* U    = (float*)ws;                  ws += 16 * F * 4;
  float* RT   = (float*)ws;                  ws += (size_t)N * NH * 4;
  unsigned int* BDT = (unsigned int*)ws;     ws += (size_t)N * NH * 4;
  float* lbuf = (float*)ws;                  ws += (size_t)N * NH * 4;

  k_pre<<<dim3(2896), dim3(256), 0, stream>>>(h, W, a, adj, hb, U, bits, out, lbuf);
  k_mid<<<dim3(1280), dim3(256), 0, stream>>>(h, U, hb, Wb, RT, BDT, gT);
  k_agg<<<dim3((N / TI) * 4 * NSPLIT), dim3(256), 0, stream>>>(
      gT, RT, BDT, bits, out, lbuf);
  k_norm<<<dim3(N * F / 4 / 256), dim3(256), 0, stream>>>(out, lbuf);
}

// Round 9
// 157.530 us; speedup vs baseline: 1.4517x; 1.0408x over previous
//
#include <hip/hip_runtime.h>
#include <math.h>

constexpr int N   = 4096;   // nodes
constexpr int F   = 256;    // IN_FEAT (= NH*HID)
constexpr int NH  = 8;      // heads
constexpr int HID = 32;     // hidden per head
constexpr float SLOPE = 0.2f;

using h2       = __attribute__((ext_vector_type(2))) _Float16;
using frag_f16 = __attribute__((ext_vector_type(8))) _Float16;  // 4 VGPRs
using frag_cd  = __attribute__((ext_vector_type(4))) float;
using frag_c16 = __attribute__((ext_vector_type(16))) float;

__device__ inline unsigned short f2h(float x) {
  _Float16 v = (_Float16)x;
  unsigned short u; __builtin_memcpy(&u, &v, 2); return u;
}

// ================= K_PRE: fused input-layer =================
// [0,544): cast h,W -> fp16 | [544,560): U = W^T a | [560,2608): adj bitmask
// [2608,2864): zero out (4 float4/thread) | [2864,2896): zero lbuf
__global__ __launch_bounds__(256) void k_pre(const float* __restrict__ h,
                                             const float* __restrict__ W,
                                             const float* __restrict__ a,
                                             const int* __restrict__ adj,
                                             unsigned short* __restrict__ hb,
                                             float* __restrict__ U,
                                             unsigned int* __restrict__ bits,
                                             float* __restrict__ outp,
                                             float* __restrict__ lbuf) {
  const int b = blockIdx.x, t = threadIdx.x;
  if (b < 544) {
    const int idx8 = (b * 256 + t) * 8;
    const float* src = (idx8 < N * F) ? (h + idx8) : (W + idx8 - N * F);
    const float4 v0 = *(const float4*)src;
    const float4 v1 = *(const float4*)(src + 4);
    unsigned short tmp[8];
    tmp[0] = f2h(v0.x); tmp[1] = f2h(v0.y); tmp[2] = f2h(v0.z); tmp[3] = f2h(v0.w);
    tmp[4] = f2h(v1.x); tmp[5] = f2h(v1.y); tmp[6] = f2h(v1.z); tmp[7] = f2h(v1.w);
    *(int4*)(hb + idx8) = *(int4*)tmp;
  } else if (b < 560) {
    const int c = b - 544, k = t;
    const int head = c & 7, side = c >> 3;
    float acc = 0.f;
#pragma unroll
    for (int f = 0; f < 32; ++f)
      acc += W[(size_t)(head * 32 + f) * F + k] * a[side * 32 + f];
    U[c * F + k] = acc;
  } else if (b < 2608) {
    const int lane = t & 63, w = t >> 6;
    const int row  = (b - 560) * 2 + (w >> 1);
    const int half = w & 1;
    const int4* arow = (const int4*)(adj + (size_t)row * N) + half * 512;
    unsigned int* brow = bits + (size_t)row * (N / 32) + half * 64;
#pragma unroll
    for (int c = 0; c < 8; ++c) {
      const int4 av = arow[c * 64 + lane];
      unsigned int v = (av.x != 0 ? 1u : 0u) | (av.y != 0 ? 2u : 0u) |
                       (av.z != 0 ? 4u : 0u) | (av.w != 0 ? 8u : 0u);
      v <<= ((lane & 7) * 4);
      v |= __shfl_xor(v, 1);
      v |= __shfl_xor(v, 2);
      v |= __shfl_xor(v, 4);
      if ((lane & 7) == 0) brow[c * 8 + (lane >> 3)] = v;
    }
  } else if (b < 2864) {
    const int base = (b - 2608) * 256 + t;
#pragma unroll
    for (int q = 0; q < 4; ++q)
      *(float4*)(outp + ((size_t)q * 65536 + base) * 4) =
          make_float4(0.f, 0.f, 0.f, 0.f);
  } else {
    *(float4*)(lbuf + ((size_t)(b - 2864) * 256 + t) * 4) =
        make_float4(0.f, 0.f, 0.f, 0.f);
  }
}

// ================= K_MID: fused second layer =================
// [0,256): s = h @ U -> RT2 = dup-packed fp16 exp(-0.8 s_l);
//          BT = fp16 exp(s_r), DT = fp16 exp(0.2 s_r)  (separate planes)
// [256,1280): gT = (hb @ Wb^T)^T fp16 via MFMA
__global__ __launch_bounds__(256) void k_mid(const float* __restrict__ h,
                                             const float* __restrict__ U,
                                             const unsigned short* __restrict__ hb,
                                             const unsigned short* __restrict__ Wb,
                                             unsigned int* __restrict__ RT2,
                                             unsigned short* __restrict__ BT,
                                             unsigned short* __restrict__ DT,
                                             unsigned short* __restrict__ gT) {
  __shared__ float hs[16][260];
  __shared__ float Us[16][260];
  const int b = blockIdx.x, t = threadIdx.x;
  if (b < 256) {
    const int i0 = b * 16;
    {
      const int r = t >> 4, s0 = (t & 15) * 16;
      const float4* src = (const float4*)(h + (size_t)(i0 + r) * F + s0);
      const float4* usr = (const float4*)(U + (size_t)r * F + s0);
#pragma unroll
      for (int q = 0; q < 4; ++q) {
        *(float4*)&hs[r][s0 + q * 4] = src[q];
        *(float4*)&Us[r][s0 + q * 4] = usr[q];
      }
    }
    __syncthreads();
    const int r = t >> 4, c = t & 15;
    float acc = 0.f;
#pragma unroll
    for (int k4 = 0; k4 < 64; ++k4) {
      const float4 hv = *(const float4*)&hs[r][k4 * 4];
      const float4 uv = *(const float4*)&Us[c][k4 * 4];
      acc += hv.x * uv.x + hv.y * uv.y + hv.z * uv.z + hv.w * uv.w;
    }
    const int n = i0 + r;
    if (c < 8) {
      const unsigned int r16 = f2h(__expf(-0.8f * acc));
      RT2[(size_t)n * NH + c] = (r16 << 16) | r16;
    } else {
      const int hd = c - 8;
      BT[(size_t)hd * N + n] = f2h(__expf(acc));
      DT[(size_t)hd * N + n] = f2h(__expf(SLOPE * acc));
    }
  } else {
    const int lane = t & 63;
    const int tile = (b - 256) * 4 + (t >> 6);
    const int mt = tile >> 4, nt = tile & 15;
    const int m0 = mt * 16, n0 = nt * 16;
    const int n16 = lane & 15, quad = lane >> 4;
    frag_cd acc = {0.f, 0.f, 0.f, 0.f};
    const unsigned short* ap = hb + (size_t)(m0 + n16) * F + quad * 8;
    const unsigned short* bp = Wb + (size_t)(n0 + n16) * F + quad * 8;
#pragma unroll
    for (int ks = 0; ks < F / 32; ++ks) {
      const frag_f16 af = *(const frag_f16*)(ap + ks * 32);
      const frag_f16 bf = *(const frag_f16*)(bp + ks * 32);
      acc = __builtin_amdgcn_mfma_f32_16x16x32_f16(af, bf, acc, 0, 0, 0);
    }
    unsigned short tmp[4];
#pragma unroll
    for (int reg = 0; reg < 4; ++reg) tmp[reg] = f2h(acc[reg]);
    *(int2*)(gT + (size_t)(n0 + n16) * N + m0 + quad * 4) = *(int2*)tmp;
  }
}

// ================= K_AGG: 32x32 fp16-MFMA flash aggregation =================
// w'_ij = adj * max(B_j, Ri*D_j) via v_pk_mul/v_pk_max on fp16 pairs.
// gT chunk in LDS; B/D prefetched to VGPRs from global (broadcast, L1-hot);
// l via v_dot2_f32_f16; wave-pair merge in LDS, then atomics.
constexpr int TI = 32;
constexpr int NSPLIT = 4;

__global__ __launch_bounds__(256, 6) void k_agg(
    const unsigned short* __restrict__ gT,
    const unsigned int* __restrict__ RT2,
    const unsigned short* __restrict__ BT, const unsigned short* __restrict__ DT,
    const unsigned int* __restrict__ bits,
    float* __restrict__ outp, float* __restrict__ lbuf) {
  __shared__ __align__(16) unsigned short sB[64][140];  // gT chunk, row=f, col=j
  __shared__ float sMl[2][32];

  const int t    = threadIdx.x;
  const int lane = t & 63;
  const int wv   = t >> 6;
  const int hd   = wv >> 1;   // head within pair
  const int jh   = wv & 1;    // j-interleave
  const int b    = blockIdx.x;
  const int hp   = b & 3;
  const int js   = (b >> 2) & (NSPLIT - 1);
  const int i0   = (b >> 4) * TI;
  const int head = hp * 2 + hd;

  const int n32 = lane & 31;
  const int kh  = lane >> 5;
  const int shmb = jh * 16 + kh * 8;  // my 8-bit window within a bits word

  const int myi = i0 + n32;
  const unsigned int Ri2u = RT2[(size_t)myi * NH + head];
  h2 Ri2; __builtin_memcpy(&Ri2, &Ri2u, 4);
  const uint4* bp4 = (const uint4*)(bits + (size_t)myi * (N / 32) + js * 32);

  const unsigned short* BTh = BT + (size_t)head * N + js * 1024;
  const unsigned short* DTh = DT + (size_t)head * N + js * 1024;

  frag_c16 acc = {0.f, 0.f, 0.f, 0.f, 0.f, 0.f, 0.f, 0.f,
                  0.f, 0.f, 0.f, 0.f, 0.f, 0.f, 0.f, 0.f};
  float lpart = 0.f;
#if __has_builtin(__builtin_amdgcn_fdot2)
  const h2 one2 = {(_Float16)1.0f, (_Float16)1.0f};
#endif

  const int sr = t >> 2, ss0 = t & 3;  // gT staging persona
  const unsigned short* gsrc = gT + (size_t)(hp * 64 + sr) * N + js * 1024;

  for (int c8 = 0; c8 < 8; ++c8) {
    __syncthreads();
    {  // stage gT 64 x 128 fp16
#pragma unroll
      for (int s = 0; s < 4; ++s) {
        const int seg = ss0 + s * 4;
        const int4 v = *(const int4*)(gsrc + c8 * 128 + seg * 8);
        *(int2*)&sB[sr][seg * 8]     = make_int2(v.x, v.y);
        *(int2*)&sB[sr][seg * 8 + 4] = make_int2(v.z, v.w);
      }
    }
    // prefetch B/D for my 4 steps (broadcast addresses, L1-hot)
    uint4 Bv[4], Dv[4];
#pragma unroll
    for (int sh = 0; sh < 4; ++sh) {
      const int jb = (sh * 2 + jh) * 16 + kh * 8;
      Bv[sh] = *(const uint4*)(BTh + c8 * 128 + jb);
      Dv[sh] = *(const uint4*)(DTh + c8 * 128 + jb);
    }
    const uint4 bw = bp4[c8];
    const unsigned int bwa[4] = {bw.x, bw.y, bw.z, bw.w};
    __syncthreads();
#pragma unroll
    for (int sh = 0; sh < 4; ++sh) {
      const int jb = (sh * 2 + jh) * 16 + kh * 8;
      const unsigned int mb = (bwa[sh] >> shmb) & 0xFFu;
      const unsigned int bu[4] = {Bv[sh].x, Bv[sh].y, Bv[sh].z, Bv[sh].w};
      const unsigned int du[4] = {Dv[sh].x, Dv[sh].y, Dv[sh].z, Dv[sh].w};
      unsigned int packed[4];
#pragma unroll
      for (int p = 0; p < 4; ++p) {
        h2 hB, hD;
        __builtin_memcpy(&hB, &bu[p], 4);
        __builtin_memcpy(&hD, &du[p], 4);
        const h2 wm = __builtin_elementwise_max(hB, Ri2 * hD);  // pk_mul + pk_max
        unsigned int wp; __builtin_memcpy(&wp, &wm, 4);
        const unsigned int d  = (mb >> (2 * p)) & 3u;
        const unsigned int sp = ((d | (d << 15)) & 0x10001u) * 0xFFFFu;
        wp &= sp;
        packed[p] = wp;
        h2 wh; __builtin_memcpy(&wh, &wp, 4);
#if __has_builtin(__builtin_amdgcn_fdot2)
        lpart = __builtin_amdgcn_fdot2(wh, one2, lpart, false);
#else
        lpart += (float)wh.x + (float)wh.y;
#endif
      }
      frag_f16 af; __builtin_memcpy(&af, packed, 16);

      const int frow = hd * 32 + n32;
      const int2 blo = *(const int2*)&sB[frow][jb];
      const int2 bhi = *(const int2*)&sB[frow][jb + 4];
      const int bt[4] = {blo.x, blo.y, bhi.x, bhi.y};
      frag_f16 bf; __builtin_memcpy(&bf, bt, 16);

      acc = __builtin_amdgcn_mfma_f32_32x32x16_f16(af, bf, acc, 0, 0, 0);
    }
  }

  // ---- merge wave pairs (jh=1 -> LDS, jh=0 adds), then atomics ----
  float* mrg = (float*)&sB[0][0];  // [2][32][32] fp32 = 8 KB (aliases sB)
  const float lp2 = lpart + __shfl_xor(lpart, 32);  // sum kh halves
  __syncthreads();
  if (jh == 1) {
#pragma unroll
    for (int reg = 0; reg < 16; ++reg) {
      const int row = (reg & 3) + 8 * (reg >> 2) + 4 * kh;
      mrg[(size_t)(hd * 32 + row) * 32 + n32] = acc[reg];
    }
    if (kh == 0) sMl[hd][n32] = lp2;
  }
  __syncthreads();
  if (jh == 0) {
    const float lt = lp2 + sMl[hd][n32];
    if (kh == 0) atomicAdd(&lbuf[(size_t)(i0 + n32) * NH + head], lt);
#pragma unroll
    for (int reg = 0; reg < 16; ++reg) {
      const int row = (reg & 3) + 8 * (reg >> 2) + 4 * kh;
      const float v = acc[reg] + mrg[(size_t)(hd * 32 + row) * 32 + n32];
      atomicAdd(&outp[(size_t)(i0 + row) * F + head * HID + n32], v);
    }
  }
}

// ================= K_NORM =================
__global__ __launch_bounds__(256) void k_norm(float* __restrict__ outp,
                                              const float* __restrict__ lbuf) {
  const int idx = blockIdx.x * 256 + threadIdx.x;  // float4 index
  const int i = idx >> 6, fq = idx & 63;
  const int hh = fq >> 3;
  const float inv = 1.f / lbuf[(size_t)i * NH + hh];
  float4 v = *(float4*)(outp + (size_t)idx * 4);
  v.x *= inv; v.y *= inv; v.z *= inv; v.w *= inv;
  *(float4*)(outp + (size_t)idx * 4) = v;
}

extern "C" void kernel_launch(void* const* d_in, const int* in_sizes, int n_in,
                              void* d_out, int out_size, void* d_ws, size_t ws_size,
                              hipStream_t stream) {
  const float* h   = (const float*)d_in[0];
  const float* W   = (const float*)d_in[1];
  const float* a   = (const float*)d_in[2];
  const int*   adj = (const int*)d_in[3];
  float* out = (float*)d_out;

  // workspace (~6.8 MB)
  char* ws = (char*)d_ws;
  unsigned short* hb = (unsigned short*)ws;  ws += (size_t)(N * F + F * F) * 2;
  unsigned short* Wb = hb + (size_t)N * F;
  unsigned short* gT = (unsigned short*)ws;  ws += (size_t)N * F * 2;
  unsigned int* bits = (unsigned int*)ws;    ws += (size_t)N * (N / 32) * 4;
  float* U    = (float*)ws;                  ws += 16 * F * 4;
  unsigned int* RT2 = (unsigned int*)ws;     ws += (size_t)N * NH * 4;
  unsigned short* BT = (unsigned short*)ws;  ws += (size_t)N * NH * 2;
  unsigned short* DT = (unsigned short*)ws;  ws += (size_t)N * NH * 2;
  float* lbuf = (float*)ws;                  ws += (size_t)N * NH * 4;

  k_pre<<<dim3(2896), dim3(256), 0, stream>>>(h, W, a, adj, hb, U, bits, out, lbuf);
  k_mid<<<dim3(1280), dim3(256), 0, stream>>>(h, U, hb, Wb, RT2, BT, DT, gT);
  k_agg<<<dim3((N / TI) * 4 * NSPLIT), dim3(256), 0, stream>>>(
      gT, RT2, BT, DT, bits, out, lbuf);
  k_norm<<<dim3(N * F / 4 / 256), dim3(256), 0, stream>>>(out, lbuf);
}